// Round 10
// baseline (82.650 us; speedup 1.0000x reference)
//
#include <hip/hip_runtime.h>
#include <hip/hip_bf16.h>
#include <stdint.h>

typedef float  f32x4  __attribute__((ext_vector_type(4)));
typedef float  f32x2  __attribute__((ext_vector_type(2)));
typedef __bf16 bf16x8 __attribute__((ext_vector_type(8)));
typedef __bf16 bf16x4 __attribute__((ext_vector_type(4)));

#define LROWF 36  // fused kernel: 72B rows -> b64 writes 8-way, b64 reads ~2-way
#define LROW  40  // (fallback kernel only)

// ---------------- weight prep: f32 -> bf16 [tensor][o][k] ----------------
__global__ __launch_bounds__(256) void wprep_kernel(
    const float* __restrict__ Wq, const float* __restrict__ Wk,
    const float* __restrict__ Wv, __bf16* __restrict__ Wbf)
{
  const int wb = blockIdx.x;           // 0..95
  const int t  = wb >> 5;
  const float* src = (t == 0) ? Wq : (t == 1) ? Wk : Wv;
  const int off = (wb & 31) * 2048 + threadIdx.x * 8;
  f32x4 v0 = *(const f32x4*)(src + off);
  f32x4 v1 = *(const f32x4*)(src + off + 4);
  bf16x8 r;
#pragma unroll
  for (int q = 0; q < 4; ++q) { r[q] = (__bf16)v0[q]; r[q + 4] = (__bf16)v1[q]; }
  *(bf16x8*)(Wbf + t * 65536 + off) = r;
}

// ---------------- fused transpose+convert+GEMM ----------------
// 128(o) x 128(px) tile, BK=32, 8 K-steps. B: reg-staged from f32 X with
// on-the-fly transpose+convert, 3-buffer LDS, ONE raw barrier per phase,
// loads issued 2 phases ahead (t+3 at body t). A: direct bf16 global loads
// (L2-resident weights), prefetched 1 phase ahead. Compiler's positional
// vmcnt waits keep younger prefetches in flight (no full drains).
__global__ __launch_bounds__(256) void gemm_fused_kernel(
    const float* __restrict__ blue, const float* __restrict__ white,
    const __bf16* __restrict__ Wbf,
    const float* __restrict__ bq, const float* __restrict__ bk,
    const float* __restrict__ bv,
    __bf16* __restrict__ Qt, __bf16* __restrict__ Kt, __bf16* __restrict__ Vt)
{
  __shared__ __bf16 Bs[3][128 * LROWF];

  // XCD-chunked; same-tile panels {K0,V0,K1,V1,Q0,Q1} adjacent (white L2 reuse)
  const int bid = blockIdx.x;                   // 1536 = 8 * 192
  const int lid = (bid & 7) * 192 + (bid >> 3);
  const int nb  = lid / 6;
  const int bt  = lid % 6;
  const int tensor = (bt < 4) ? 1 + (bt & 1) : 0;   // 0:Q 1:K 2:V
  const int ob     = (bt < 4) ? (bt >> 1) : (bt & 1);

  const float*  X    = (tensor == 0) ? blue : white;
  const float*  bias = (tensor == 0) ? bq : (tensor == 1) ? bk : bv;
  __bf16*       Out  = (tensor == 0) ? Qt : (tensor == 1) ? Kt : Vt;
  const __bf16* Wp   = Wbf + tensor * 65536 + ob * 32768;

  const int tid  = threadIdx.x;
  const int lane = tid & 63;
  const int w    = tid >> 6;
  const int wo   = w >> 1;
  const int wn   = w & 1;
  const int lrow = lane & 15;
  const int lks  = lane >> 4;

  const int o0    = ob * 128;
  const int n0    = nb * 128;
  const int batch = n0 >> 12;
  const int p0    = n0 & 4095;
  const int tk0   = p0 >> 4;
  const int trow  = tk0 >> 4;
  const int tcol0 = tk0 & 15;
  const float* Xb = X + (size_t)batch * (256 * 4096);

  // B-staging role (verified round-2 mapping): thread = (px-pair, k-octet)
  const int n2   = tid & 63;
  const int ko   = tid >> 6;
  const int nloc = 2 * n2;
  const int tl   = nloc >> 4;
  const int d    = nloc & 15;
  const int hw   = (trow * 4 + (d >> 2)) * 64 + (tcol0 + tl) * 4 + (d & 3);
  const float* srcB = Xb + (size_t)(ko * 8) * 4096 + hw;   // + kk*32*4096

  // A fragment addressing (direct global bf16)
  const __bf16* abase = Wp + (size_t)(wo * 64 + lrow) * 256 + lks * 8; // +i*16*256 +kk*32

  f32x4 acc[4][4];
#pragma unroll
  for (int i = 0; i < 4; ++i)
#pragma unroll
    for (int j = 0; j < 4; ++j) acc[i][j] = (f32x4)0.0f;

  f32x2  pA[8], pB[8];        // 2-set B register staging
  bf16x8 afA[4], afB[4];      // 2-set A fragments

#define LOADB(P, kk) do { const float* s_ = srcB + (size_t)(kk) * 32 * 4096;   \
    P[0] = *(const f32x2*)(s_);         P[1] = *(const f32x2*)(s_ + 4096);     \
    P[2] = *(const f32x2*)(s_ + 8192);  P[3] = *(const f32x2*)(s_ + 12288);    \
    P[4] = *(const f32x2*)(s_ + 16384); P[5] = *(const f32x2*)(s_ + 20480);    \
    P[6] = *(const f32x2*)(s_ + 24576); P[7] = *(const f32x2*)(s_ + 28672);    \
  } while (0)

#define LOADA(AF, kk) do {                                                     \
    _Pragma("unroll")                                                          \
    for (int i = 0; i < 4; ++i)                                                \
      AF[i] = *(const bf16x8*)(abase + (size_t)i * 16 * 256 + (kk) * 32);      \
  } while (0)

#define WRITEB(P, BUF) do {                                                    \
    __bf16* bp = &Bs[BUF][nloc * LROWF + ko * 8];                              \
    bf16x4 a0, a1, b0, b1;                                                     \
    a0[0] = (__bf16)P[0][0]; a0[1] = (__bf16)P[1][0];                          \
    a0[2] = (__bf16)P[2][0]; a0[3] = (__bf16)P[3][0];                          \
    a1[0] = (__bf16)P[4][0]; a1[1] = (__bf16)P[5][0];                          \
    a1[2] = (__bf16)P[6][0]; a1[3] = (__bf16)P[7][0];                          \
    b0[0] = (__bf16)P[0][1]; b0[1] = (__bf16)P[1][1];                          \
    b0[2] = (__bf16)P[2][1]; b0[3] = (__bf16)P[3][1];                          \
    b1[0] = (__bf16)P[4][1]; b1[1] = (__bf16)P[5][1];                          \
    b1[2] = (__bf16)P[6][1]; b1[3] = (__bf16)P[7][1];                          \
    *(bf16x4*)(bp)             = a0;  *(bf16x4*)(bp + 4)         = a1;         \
    *(bf16x4*)(bp + LROWF)     = b0;  *(bf16x4*)(bp + LROWF + 4) = b1;         \
  } while (0)

#define COMPUTE(BUF, AF) do {                                                  \
    bf16x8 bfr[4];                                                             \
    _Pragma("unroll")                                                          \
    for (int j = 0; j < 4; ++j) {                                              \
      const int row = wn * 64 + j * 16 + lrow;                                 \
      bf16x4 x0 = *(const bf16x4*)&Bs[BUF][row * LROWF + lks * 8];             \
      bf16x4 x1 = *(const bf16x4*)&Bs[BUF][row * LROWF + lks * 8 + 4];         \
      bf16x8 v;                                                                \
      v[0] = x0[0]; v[1] = x0[1]; v[2] = x0[2]; v[3] = x0[3];                  \
      v[4] = x1[0]; v[5] = x1[1]; v[6] = x1[2]; v[7] = x1[3];                  \
      bfr[j] = v;                                                              \
    }                                                                          \
    __builtin_amdgcn_s_setprio(1);                                             \
    _Pragma("unroll")                                                          \
    for (int i = 0; i < 4; ++i)                                                \
      _Pragma("unroll")                                                        \
      for (int j = 0; j < 4; ++j)                                              \
        acc[i][j] = __builtin_amdgcn_mfma_f32_16x16x32_bf16(AF[i], bfr[j],     \
                                                            acc[i][j], 0, 0, 0);\
    __builtin_amdgcn_s_setprio(0);                                             \
  } while (0)

#define BAR() do {                                                             \
    asm volatile("s_waitcnt lgkmcnt(0)" ::: "memory");                         \
    __builtin_amdgcn_sched_barrier(0);                                         \
    __builtin_amdgcn_s_barrier();                                              \
    __builtin_amdgcn_sched_barrier(0);                                         \
  } while (0)

  // prologue: loads 0,1,2 (2-deep sets + refill), write 0, af 0
  LOADB(pA, 0);
  LOADB(pB, 1);
  LOADA(afA, 0);
  WRITEB(pA, 0);          // auto vmcnt waits pA only (pB, afA younger)
  LOADB(pA, 2);
  BAR();

  // body(t): af(t+1) | write(t+1) | loads(t+3) | barrier | compute(t)
#define BODY(T, PW, AFN, AFC) do {                                             \
    if ((T) < 7) LOADA(AFN, (T) + 1);                                          \
    if ((T) < 7) WRITEB(PW, ((T) + 1) % 3);                                    \
    if ((T) < 5) LOADB(PW, (T) + 3);                                           \
    BAR();                                                                     \
    COMPUTE((T) % 3, AFC);                                                     \
  } while (0)

  BODY(0, pB, afB, afA);
  BODY(1, pA, afA, afB);
  BODY(2, pB, afB, afA);
  BODY(3, pA, afA, afB);
  BODY(4, pB, afB, afA);
  BODY(5, pA, afA, afB);
  BODY(6, pB, afB, afA);
  BODY(7, pA, afA, afB);   // tail: no stage, barrier harmless
#undef BODY
#undef BAR
#undef COMPUTE
#undef WRITEB
#undef LOADA
#undef LOADB

  // ---- epilogue: bias add, write bf16 layout [b][ti][c][tj][16]
#pragma unroll
  for (int i = 0; i < 4; ++i) {
    const int obase = o0 + wo * 64 + i * 16 + (lane >> 4) * 4;
#pragma unroll
    for (int j = 0; j < 4; ++j) {
      const int n  = n0 + wn * 64 + j * 16 + (lane & 15);
      const int bb = n >> 12;
      const int pp = n & 4095;
      const int tt = pp >> 4;
      const int tii = tt >> 4;
      const int tjj = tt & 15;
      const int dd  = pp & 15;
      const size_t base = ((size_t)(bb * 16 + tii) * 256) * 256 + tjj * 16 + dd;
#pragma unroll
      for (int r = 0; r < 4; ++r) {
        const int o = obase + r;
        const float v = acc[i][j][r] + bias[o];
        Out[base + (size_t)o * 256] = (__bf16)v;
      }
    }
  }
}

// ---------------- fallback: round-2 self-contained projection ----------------
__global__ __launch_bounds__(256) void proj_gemm_kernel(
    const float* __restrict__ blue, const float* __restrict__ white,
    const float* __restrict__ Wq, const float* __restrict__ bq,
    const float* __restrict__ Wk, const float* __restrict__ bk,
    const float* __restrict__ Wv, const float* __restrict__ bv,
    __bf16* __restrict__ Qt, __bf16* __restrict__ Kt, __bf16* __restrict__ Vt)
{
  __shared__ __bf16 As[128 * LROW];
  __shared__ __bf16 Bs[128 * LROW];

  const int bidhw = blockIdx.x;
  const int lid   = (bidhw & 7) * 192 + (bidhw >> 3);
  const int nb    = lid / 6;
  const int bt    = lid % 6;
  const int tensor = (bt < 4) ? 1 + (bt & 1) : 0;
  const int ob     = (bt < 4) ? (bt >> 1) : (bt & 1);

  const float* X    = (tensor == 0) ? blue : white;
  const float* W    = (tensor == 0) ? Wq : (tensor == 1) ? Wk : Wv;
  const float* bias = (tensor == 0) ? bq : (tensor == 1) ? bk : bv;
  __bf16*      Out  = (tensor == 0) ? Qt : (tensor == 1) ? Kt : Vt;

  const int tid  = threadIdx.x;
  const int lane = tid & 63;
  const int wave = tid >> 6;
  const int wo   = wave >> 1;
  const int wn   = wave & 1;

  const int o0 = ob * 128;
  const int n0 = nb * 128;
  const int batch = n0 >> 12;
  const int p0    = n0 & 4095;
  const int tk0   = p0 >> 4;
  const int trow  = tk0 >> 4;
  const int tcol0 = tk0 & 15;
  const float* Xb = X + (size_t)batch * (256 * 4096);

  f32x4 acc[4][4];
#pragma unroll
  for (int i = 0; i < 4; ++i)
#pragma unroll
    for (int j = 0; j < 4; ++j) acc[i][j] = (f32x4)0.0f;

  const int arow  = tid >> 1;
  const int ahalf = tid & 1;
  const int n2   = tid & 63;
  const int ko   = tid >> 6;
  const int nloc = 2 * n2;
  const int tl   = nloc >> 4;
  const int d    = nloc & 15;
  const int hw   = (trow * 4 + (d >> 2)) * 64 + (tcol0 + tl) * 4 + (d & 3);

  const int lrow = lane & 15;
  const int lk   = (lane >> 4) * 8;

  for (int kk = 0; kk < 8; ++kk) {
    const int k0 = kk * 32;
    {
      const float* src = W + (size_t)(o0 + arow) * 256 + k0 + ahalf * 16;
      f32x4 t0 = *(const f32x4*)(src + 0);
      f32x4 t1 = *(const f32x4*)(src + 4);
      f32x4 t2 = *(const f32x4*)(src + 8);
      f32x4 t3 = *(const f32x4*)(src + 12);
      bf16x8 c0, c1;
#pragma unroll
      for (int qq = 0; qq < 4; ++qq) { c0[qq] = (__bf16)t0[qq]; c0[qq + 4] = (__bf16)t1[qq]; }
#pragma unroll
      for (int qq = 0; qq < 4; ++qq) { c1[qq] = (__bf16)t2[qq]; c1[qq + 4] = (__bf16)t3[qq]; }
      __bf16* dst = As + arow * LROW + ahalf * 16;
      *(bf16x8*)(dst + 0) = c0;
      *(bf16x8*)(dst + 8) = c1;
    }
    {
      const float* src = Xb + (size_t)(k0 + ko * 8) * 4096 + hw;
      f32x2 v0 = *(const f32x2*)(src + 0 * 4096);
      f32x2 v1 = *(const f32x2*)(src + 1 * 4096);
      f32x2 v2 = *(const f32x2*)(src + 2 * 4096);
      f32x2 v3 = *(const f32x2*)(src + 3 * 4096);
      f32x2 v4 = *(const f32x2*)(src + 4 * 4096);
      f32x2 v5 = *(const f32x2*)(src + 5 * 4096);
      f32x2 v6 = *(const f32x2*)(src + 6 * 4096);
      f32x2 v7 = *(const f32x2*)(src + 7 * 4096);
      bf16x8 r0, r1;
      r0[0] = (__bf16)v0[0]; r0[1] = (__bf16)v1[0]; r0[2] = (__bf16)v2[0]; r0[3] = (__bf16)v3[0];
      r0[4] = (__bf16)v4[0]; r0[5] = (__bf16)v5[0]; r0[6] = (__bf16)v6[0]; r0[7] = (__bf16)v7[0];
      r1[0] = (__bf16)v0[1]; r1[1] = (__bf16)v1[1]; r1[2] = (__bf16)v2[1]; r1[3] = (__bf16)v3[1];
      r1[4] = (__bf16)v4[1]; r1[5] = (__bf16)v5[1]; r1[6] = (__bf16)v6[1]; r1[7] = (__bf16)v7[1];
      *(bf16x8*)(Bs + (nloc + 0) * LROW + ko * 8) = r0;
      *(bf16x8*)(Bs + (nloc + 1) * LROW + ko * 8) = r1;
    }
    __syncthreads();

    bf16x8 a[4], b[4];
#pragma unroll
    for (int i = 0; i < 4; ++i)
      a[i] = *(const bf16x8*)(As + (wo * 64 + i * 16 + lrow) * LROW + lk);
#pragma unroll
    for (int j = 0; j < 4; ++j)
      b[j] = *(const bf16x8*)(Bs + (wn * 64 + j * 16 + lrow) * LROW + lk);
#pragma unroll
    for (int i = 0; i < 4; ++i)
#pragma unroll
      for (int j = 0; j < 4; ++j)
        acc[i][j] = __builtin_amdgcn_mfma_f32_16x16x32_bf16(a[i], b[j], acc[i][j], 0, 0, 0);
    __syncthreads();
  }

#pragma unroll
  for (int i = 0; i < 4; ++i) {
    const int obase = o0 + wo * 64 + i * 16 + (lane >> 4) * 4;
#pragma unroll
    for (int j = 0; j < 4; ++j) {
      const int n  = n0 + wn * 64 + j * 16 + (lane & 15);
      const int bb = n >> 12;
      const int p  = n & 4095;
      const int tt = p >> 4;
      const int tii = tt >> 4;
      const int tjj = tt & 15;
      const int dd  = p & 15;
      const size_t base = ((size_t)(bb * 16 + tii) * 256) * 256 + tjj * 16 + dd;
#pragma unroll
      for (int r = 0; r < 4; ++r) {
        const int o = obase + r;
        const float v = acc[i][j][r] + bias[o];
        Out[base + (size_t)o * 256] = (__bf16)v;
      }
    }
  }
}

// ---------------- fused neighborhood attention + residual ----------------
__device__ __forceinline__ void unpack8(const uint4 v, float* f) {
  const uint32_t u0 = v.x, u1 = v.y, u2 = v.z, u3 = v.w;
  f[0] = __uint_as_float(u0 << 16); f[1] = __uint_as_float(u0 & 0xffff0000u);
  f[2] = __uint_as_float(u1 << 16); f[3] = __uint_as_float(u1 & 0xffff0000u);
  f[4] = __uint_as_float(u2 << 16); f[5] = __uint_as_float(u2 & 0xffff0000u);
  f[6] = __uint_as_float(u3 << 16); f[7] = __uint_as_float(u3 & 0xffff0000u);
}

__global__ __launch_bounds__(256) void attn_kernel(
    const __bf16* __restrict__ Qt, const __bf16* __restrict__ Kt,
    const __bf16* __restrict__ Vt, const float* __restrict__ blue,
    float* __restrict__ out)
{
  const int j   = blockIdx.x;
  const int bid = (j & 7) * 256 + (j >> 3);
  const int cg  = bid & 15;
  const int ti  = (bid >> 4) & 15;
  const int b   = bid >> 8;

  const int tid = threadIdx.x;
  const int tj  = tid & 15;
  const int cl  = tid >> 4;
  const int c   = cg * 16 + cl;

  float q[16];
  {
    const __bf16* p = Qt + ((((size_t)b * 16 + ti) * 256 + c) * 16 + tj) * 16;
    unpack8(*(const uint4*)p, q);
    unpack8(*(const uint4*)(p + 8), q + 8);
  }

  float s[9];
#pragma unroll
  for (int n = 0; n < 9; ++n) {
    const int yi = ti + n / 3 - 1;
    const int yj = tj + n % 3 - 1;
    float dot = 0.0f;
    if (yi >= 0 && yi < 16 && yj >= 0 && yj < 16) {
      const __bf16* p = Kt + ((((size_t)b * 16 + yi) * 256 + c) * 16 + yj) * 16;
      float kf[16];
      unpack8(*(const uint4*)p, kf);
      unpack8(*(const uint4*)(p + 8), kf + 8);
#pragma unroll
      for (int dd = 0; dd < 16; ++dd) dot = fmaf(q[dd], kf[dd], dot);
    }
    s[n] = dot * 0.25f;
  }

  float m = s[0];
#pragma unroll
  for (int n = 1; n < 9; ++n) m = fmaxf(m, s[n]);
  float w[9], denom = 0.0f;
#pragma unroll
  for (int n = 0; n < 9; ++n) { w[n] = __expf(s[n] - m); denom += w[n]; }
  const float inv = 1.0f / denom;

  float o16[16];
#pragma unroll
  for (int dd = 0; dd < 16; ++dd) o16[dd] = 0.0f;
#pragma unroll
  for (int n = 0; n < 9; ++n) {
    const int yi = ti + n / 3 - 1;
    const int yj = tj + n % 3 - 1;
    if (yi >= 0 && yi < 16 && yj >= 0 && yj < 16) {
      const __bf16* p = Vt + ((((size_t)b * 16 + yi) * 256 + c) * 16 + yj) * 16;
      float vf[16];
      unpack8(*(const uint4*)p, vf);
      unpack8(*(const uint4*)(p + 8), vf + 8);
#pragma unroll
      for (int dd = 0; dd < 16; ++dd) o16[dd] = fmaf(w[n], vf[dd], o16[dd]);
    }
  }

  const size_t pbase = ((size_t)b * 256 + c) * 4096 + (size_t)(ti * 4) * 64 + tj * 4;
#pragma unroll
  for (int r = 0; r < 4; ++r) {
    f32x4 bl = *(const f32x4*)(blue + pbase + r * 64);
    f32x4 ov;
#pragma unroll
    for (int j2 = 0; j2 < 4; ++j2) ov[j2] = bl[j2] + o16[r * 4 + j2] * inv;
    *(f32x4*)(out + pbase + r * 64) = ov;
  }
}

// ---------------- launcher ----------------
extern "C" void kernel_launch(void* const* d_in, const int* in_sizes, int n_in,
                              void* d_out, int out_size, void* d_ws, size_t ws_size,
                              hipStream_t stream) {
  const float* blue  = (const float*)d_in[0];
  const float* white = (const float*)d_in[1];
  const float* Wq = (const float*)d_in[2];
  const float* bq = (const float*)d_in[3];
  const float* Wk = (const float*)d_in[4];
  const float* bk = (const float*)d_in[5];
  const float* Wv = (const float*)d_in[6];
  const float* bv = (const float*)d_in[7];
  float* out = (float*)d_out;

  const size_t tsz = (size_t)8 * 256 * 256 * 16;   // QKV elems per tensor
  __bf16* Qt = (__bf16*)d_ws;
  __bf16* Kt = Qt + tsz;
  __bf16* Vt = Kt + tsz;

  const size_t need = (3 * tsz + 3 * 65536) * sizeof(__bf16);
  if (ws_size >= need) {
    __bf16* Wbf = Vt + tsz;
    wprep_kernel<<<96, 256, 0, stream>>>(Wq, Wk, Wv, Wbf);
    gemm_fused_kernel<<<1536, 256, 0, stream>>>(blue, white, Wbf, bq, bk, bv, Qt, Kt, Vt);
  } else {
    proj_gemm_kernel<<<1536, 256, 0, stream>>>(blue, white, Wq, bq, Wk, bk, Wv, bv, Qt, Kt, Vt);
  }
  attn_kernel<<<2048, 256, 0, stream>>>(Qt, Kt, Vt, blue, out);
}

// Round 11
// 72.692 us; speedup vs baseline: 1.1370x; 1.1370x over previous
//
#include <hip/hip_runtime.h>
#include <hip/hip_bf16.h>
#include <stdint.h>

typedef float  f32x4  __attribute__((ext_vector_type(4)));
typedef float  f32x2  __attribute__((ext_vector_type(2)));
typedef __bf16 bf16x8 __attribute__((ext_vector_type(8)));

#define LROW 40   // (fallback kernel only)

// ---------------- weight prep: f32 -> bf16 [tensor][o][k] ----------------
__global__ __launch_bounds__(256) void wprep_kernel(
    const float* __restrict__ Wq, const float* __restrict__ Wk,
    const float* __restrict__ Wv, __bf16* __restrict__ Wbf)
{
  const int wb = blockIdx.x;           // 0..95
  const int t  = wb >> 5;
  const float* src = (t == 0) ? Wq : (t == 1) ? Wk : Wv;
  const int off = (wb & 31) * 2048 + threadIdx.x * 8;
  f32x4 v0 = *(const f32x4*)(src + off);
  f32x4 v1 = *(const f32x4*)(src + off + 4);
  bf16x8 r;
#pragma unroll
  for (int q = 0; q < 4; ++q) { r[q] = (__bf16)v0[q]; r[q + 4] = (__bf16)v1[q]; }
  *(bf16x8*)(Wbf + t * 65536 + off) = r;
}

// ---------------- fused GEMM: f32 X staged via global_load_lds ----------------
// 128(o) x 128(px) tile, BK=32, 8 K-steps, TRIPLE-buffered LDS.
// B: f32 [32k][128px] tiles DMA'd straight from X (per-lane source addresses
//    perform the transpose; 16-px rotation per 8-row group makes fragment
//    reads 2-way conflict-free). f32->bf16 conversion on the LDS->reg path.
// A: bf16 weights (wprep) via verified R8 swizzled global_load_lds.
// Sync: R9's counted-vmcnt PHASE skeleton (6 loads/stage -> 12/6/0).

#define GLOAD16(GS, LD) \
  __builtin_amdgcn_global_load_lds( \
      (const __attribute__((address_space(1))) uint32_t*)(GS), \
      (__attribute__((address_space(3))) uint32_t*)(LD), 16, 0, 0)

__global__ __launch_bounds__(256) void gemm_f32lds_kernel(
    const float* __restrict__ blue, const float* __restrict__ white,
    const __bf16* __restrict__ Wbf,
    const float* __restrict__ bq, const float* __restrict__ bk,
    const float* __restrict__ bv,
    __bf16* __restrict__ Qt, __bf16* __restrict__ Kt, __bf16* __restrict__ Vt)
{
  __shared__ float  Bsf[3][32 * 128];    // 3 x 16 KB
  __shared__ __bf16 As[3][128 * 32];     // 3 x 8 KB

  // XCD-chunked; same-tile panels {K0,V0,K1,V1,Q0,Q1} adjacent (white L2 reuse)
  const int bid = blockIdx.x;                   // 1536 = 8 * 192
  const int lid = (bid & 7) * 192 + (bid >> 3);
  const int nb  = lid / 6;
  const int bt  = lid % 6;
  const int tensor = (bt < 4) ? 1 + (bt & 1) : 0;   // 0:Q 1:K 2:V
  const int ob     = (bt < 4) ? (bt >> 1) : (bt & 1);

  const float*  X    = (tensor == 0) ? blue : white;
  const float*  bias = (tensor == 0) ? bq : (tensor == 1) ? bk : bv;
  __bf16*       Out  = (tensor == 0) ? Qt : (tensor == 1) ? Kt : Vt;
  const __bf16* Wp   = Wbf + tensor * 65536 + ob * 32768;

  const int tid  = threadIdx.x;
  const int lane = tid & 63;
  const int w    = tid >> 6;
  const int wo   = w >> 1;
  const int wn   = w & 1;
  const int lrow = lane & 15;
  const int lks  = lane >> 4;

  const int o0    = ob * 128;
  const int n0    = nb * 128;
  const int batch = n0 >> 12;
  const int p0    = n0 & 4095;
  const int tk0   = p0 >> 4;
  const int trow  = tk0 >> 4;
  const int tcol0 = tk0 & 15;
  const float* Xb = X + (size_t)batch * (256 * 4096);

  // ---- B staging: instruction c = m*4 + w covers rows {2c, 2c+1} of the
  // [32][128] f32 tile. lane l: row 2c+(l>>5), px-quad q=l&31.
  // Source rotation: px_src = (q*4 + 16*(c>>2)) & 127  (g = row>>3 = c>>2).
  const float* gB[4];
#pragma unroll
  for (int m = 0; m < 4; ++m) {
    const int c      = m * 4 + w;
    const int krow   = 2 * c + (lane >> 5);
    const int g      = c >> 2;
    const int px_src = ((lane & 31) * 4 + 16 * g) & 127;
    const int tl     = px_src >> 4;
    const int d      = px_src & 15;
    const int hw     = (trow * 4 + (d >> 2)) * 64 + (tcol0 + tl) * 4 + (d & 3);
    gB[m] = Xb + (size_t)krow * 4096 + hw;          // + kk*32*4096 per step
  }

  // ---- A staging (verified R8 pattern)
  const int rA    = w * 16 + (lane >> 2);
  const int gslot = (lane & 3) ^ ((lane >> 3) & 3);
  const __bf16* gA = Wp + (size_t)rA * 256 + gslot * 8;
  const int ldsOffQ0 = (w * 16) * 32;
  const int ldsOffQ1 = (64 + w * 16) * 32;

#define STAGE(BUF, KK) do {                                          \
    GLOAD16(gA + (KK) * 32,            &As[BUF][ldsOffQ0]);          \
    GLOAD16(gA + 64 * 256 + (KK) * 32, &As[BUF][ldsOffQ1]);          \
    GLOAD16(gB[0] + (size_t)(KK) * 32 * 4096, &Bsf[BUF][(0 * 4 + w) * 256]); \
    GLOAD16(gB[1] + (size_t)(KK) * 32 * 4096, &Bsf[BUF][(1 * 4 + w) * 256]); \
    GLOAD16(gB[2] + (size_t)(KK) * 32 * 4096, &Bsf[BUF][(2 * 4 + w) * 256]); \
    GLOAD16(gB[3] + (size_t)(KK) * 32 * 4096, &Bsf[BUF][(3 * 4 + w) * 256]); \
  } while (0)

  // ---- fragment read addressing
  const int sxA = (lks ^ ((lrow >> 1) & 3)) * 8;    // A swizzle (R8)
  const int pxb = wn * 64 + lrow;                   // B: s_j = (pxb + j*16 - 16*lks) & 127

  f32x4 acc[4][4];
#pragma unroll
  for (int i = 0; i < 4; ++i)
#pragma unroll
    for (int j = 0; j < 4; ++j) acc[i][j] = (f32x4)0.0f;

#define COMPUTE(BUF) do {                                                       \
    bf16x8 af[4], bfr[4];                                                       \
    _Pragma("unroll")                                                           \
    for (int i = 0; i < 4; ++i)                                                 \
      af[i] = *(const bf16x8*)&As[BUF][(wo * 64 + i * 16 + lrow) * 32 + sxA];   \
    _Pragma("unroll")                                                           \
    for (int j = 0; j < 4; ++j) {                                               \
      const int s = (pxb + j * 16 - 16 * lks + 128) & 127;                      \
      const float* bp = &Bsf[BUF][lks * 8 * 128 + s];                           \
      bf16x8 v;                                                                 \
      _Pragma("unroll")                                                         \
      for (int kk = 0; kk < 8; ++kk) v[kk] = (__bf16)bp[kk * 128];              \
      bfr[j] = v;                                                               \
    }                                                                           \
    __builtin_amdgcn_s_setprio(1);                                              \
    _Pragma("unroll")                                                           \
    for (int i = 0; i < 4; ++i)                                                 \
      _Pragma("unroll")                                                         \
      for (int j = 0; j < 4; ++j)                                               \
        acc[i][j] = __builtin_amdgcn_mfma_f32_16x16x32_bf16(af[i], bfr[j],      \
                                                            acc[i][j], 0, 0, 0);\
    __builtin_amdgcn_s_setprio(0);                                              \
  } while (0)

  STAGE(0, 0);
  STAGE(1, 1);
  STAGE(2, 2);

#define PHASE(T) do {                                                           \
    if ((T) == 7)      asm volatile("s_waitcnt vmcnt(0)"  ::: "memory");        \
    else if ((T) == 6) asm volatile("s_waitcnt vmcnt(6)"  ::: "memory");        \
    else               asm volatile("s_waitcnt vmcnt(12)" ::: "memory");        \
    __builtin_amdgcn_sched_barrier(0);                                          \
    __builtin_amdgcn_s_barrier();                                               \
    __builtin_amdgcn_sched_barrier(0);                                          \
    COMPUTE((T) % 3);                                                           \
    asm volatile("s_waitcnt lgkmcnt(0)" ::: "memory");                          \
    __builtin_amdgcn_sched_barrier(0);                                          \
    __builtin_amdgcn_s_barrier();                                               \
    __builtin_amdgcn_sched_barrier(0);                                          \
    if ((T) < 5) STAGE((T) % 3, (T) + 3);                                       \
  } while (0)

  PHASE(0); PHASE(1); PHASE(2); PHASE(3);
  PHASE(4); PHASE(5); PHASE(6); PHASE(7);
#undef PHASE
#undef STAGE
#undef COMPUTE

  // ---- epilogue: bias add, write bf16 layout [b][ti][c][tj][16]
#pragma unroll
  for (int i = 0; i < 4; ++i) {
    const int obase = o0 + wo * 64 + i * 16 + (lane >> 4) * 4;
#pragma unroll
    for (int j = 0; j < 4; ++j) {
      const int n  = n0 + wn * 64 + j * 16 + (lane & 15);
      const int bb = n >> 12;
      const int pp = n & 4095;
      const int tt = pp >> 4;
      const int tii = tt >> 4;
      const int tjj = tt & 15;
      const int dd  = pp & 15;
      const size_t base = ((size_t)(bb * 16 + tii) * 256) * 256 + tjj * 16 + dd;
#pragma unroll
      for (int r = 0; r < 4; ++r) {
        const int o = obase + r;
        const float v = acc[i][j][r] + bias[o];
        Out[base + (size_t)o * 256] = (__bf16)v;
      }
    }
  }
}

// ---------------- fallback: round-2 self-contained projection ----------------
__global__ __launch_bounds__(256) void proj_gemm_kernel(
    const float* __restrict__ blue, const float* __restrict__ white,
    const float* __restrict__ Wq, const float* __restrict__ bq,
    const float* __restrict__ Wk, const float* __restrict__ bk,
    const float* __restrict__ Wv, const float* __restrict__ bv,
    __bf16* __restrict__ Qt, __bf16* __restrict__ Kt, __bf16* __restrict__ Vt)
{
  __shared__ __bf16 As[128 * LROW];
  __shared__ __bf16 Bs[128 * LROW];

  const int bidhw = blockIdx.x;
  const int lid   = (bidhw & 7) * 192 + (bidhw >> 3);
  const int nb    = lid / 6;
  const int bt    = lid % 6;
  const int tensor = (bt < 4) ? 1 + (bt & 1) : 0;
  const int ob     = (bt < 4) ? (bt >> 1) : (bt & 1);

  const float* X    = (tensor == 0) ? blue : white;
  const float* W    = (tensor == 0) ? Wq : (tensor == 1) ? Wk : Wv;
  const float* bias = (tensor == 0) ? bq : (tensor == 1) ? bk : bv;
  __bf16*      Out  = (tensor == 0) ? Qt : (tensor == 1) ? Kt : Vt;

  const int tid  = threadIdx.x;
  const int lane = tid & 63;
  const int wave = tid >> 6;
  const int wo   = wave >> 1;
  const int wn   = wave & 1;

  const int o0 = ob * 128;
  const int n0 = nb * 128;
  const int batch = n0 >> 12;
  const int p0    = n0 & 4095;
  const int tk0   = p0 >> 4;
  const int trow  = tk0 >> 4;
  const int tcol0 = tk0 & 15;
  const float* Xb = X + (size_t)batch * (256 * 4096);

  f32x4 acc[4][4];
#pragma unroll
  for (int i = 0; i < 4; ++i)
#pragma unroll
    for (int j = 0; j < 4; ++j) acc[i][j] = (f32x4)0.0f;

  const int arow  = tid >> 1;
  const int ahalf = tid & 1;
  const int n2   = tid & 63;
  const int ko   = tid >> 6;
  const int nloc = 2 * n2;
  const int tl   = nloc >> 4;
  const int d    = nloc & 15;
  const int hw   = (trow * 4 + (d >> 2)) * 64 + (tcol0 + tl) * 4 + (d & 3);

  const int lrow = lane & 15;
  const int lk   = (lane >> 4) * 8;

  for (int kk = 0; kk < 8; ++kk) {
    const int k0 = kk * 32;
    {
      const float* src = W + (size_t)(o0 + arow) * 256 + k0 + ahalf * 16;
      f32x4 t0 = *(const f32x4*)(src + 0);
      f32x4 t1 = *(const f32x4*)(src + 4);
      f32x4 t2 = *(const f32x4*)(src + 8);
      f32x4 t3 = *(const f32x4*)(src + 12);
      bf16x8 c0, c1;
#pragma unroll
      for (int qq = 0; qq < 4; ++qq) { c0[qq] = (__bf16)t0[qq]; c0[qq + 4] = (__bf16)t1[qq]; }
#pragma unroll
      for (int qq = 0; qq < 4; ++qq) { c1[qq] = (__bf16)t2[qq]; c1[qq + 4] = (__bf16)t3[qq]; }
      __bf16* dst = As + arow * LROW + ahalf * 16;
      *(bf16x8*)(dst + 0) = c0;
      *(bf16x8*)(dst + 8) = c1;
    }
    {
      const float* src = Xb + (size_t)(k0 + ko * 8) * 4096 + hw;
      f32x2 v0 = *(const f32x2*)(src + 0 * 4096);
      f32x2 v1 = *(const f32x2*)(src + 1 * 4096);
      f32x2 v2 = *(const f32x2*)(src + 2 * 4096);
      f32x2 v3 = *(const f32x2*)(src + 3 * 4096);
      f32x2 v4 = *(const f32x2*)(src + 4 * 4096);
      f32x2 v5 = *(const f32x2*)(src + 5 * 4096);
      f32x2 v6 = *(const f32x2*)(src + 6 * 4096);
      f32x2 v7 = *(const f32x2*)(src + 7 * 4096);
      bf16x8 r0, r1;
      r0[0] = (__bf16)v0[0]; r0[1] = (__bf16)v1[0]; r0[2] = (__bf16)v2[0]; r0[3] = (__bf16)v3[0];
      r0[4] = (__bf16)v4[0]; r0[5] = (__bf16)v5[0]; r0[6] = (__bf16)v6[0]; r0[7] = (__bf16)v7[0];
      r1[0] = (__bf16)v0[1]; r1[1] = (__bf16)v1[1]; r1[2] = (__bf16)v2[1]; r1[3] = (__bf16)v3[1];
      r1[4] = (__bf16)v4[1]; r1[5] = (__bf16)v5[1]; r1[6] = (__bf16)v6[1]; r1[7] = (__bf16)v7[1];
      *(bf16x8*)(Bs + (nloc + 0) * LROW + ko * 8) = r0;
      *(bf16x8*)(Bs + (nloc + 1) * LROW + ko * 8) = r1;
    }
    __syncthreads();

    bf16x8 a[4], b[4];
#pragma unroll
    for (int i = 0; i < 4; ++i)
      a[i] = *(const bf16x8*)(As + (wo * 64 + i * 16 + lrow) * LROW + lk);
#pragma unroll
    for (int j = 0; j < 4; ++j)
      b[j] = *(const bf16x8*)(Bs + (wn * 64 + j * 16 + lrow) * LROW + lk);
#pragma unroll
    for (int i = 0; i < 4; ++i)
#pragma unroll
      for (int j = 0; j < 4; ++j)
        acc[i][j] = __builtin_amdgcn_mfma_f32_16x16x32_bf16(a[i], b[j], acc[i][j], 0, 0, 0);
    __syncthreads();
  }

#pragma unroll
  for (int i = 0; i < 4; ++i) {
    const int obase = o0 + wo * 64 + i * 16 + (lane >> 4) * 4;
#pragma unroll
    for (int j = 0; j < 4; ++j) {
      const int n  = n0 + wn * 64 + j * 16 + (lane & 15);
      const int bb = n >> 12;
      const int p  = n & 4095;
      const int tt = p >> 4;
      const int tii = tt >> 4;
      const int tjj = tt & 15;
      const int dd  = p & 15;
      const size_t base = ((size_t)(bb * 16 + tii) * 256) * 256 + tjj * 16 + dd;
#pragma unroll
      for (int r = 0; r < 4; ++r) {
        const int o = obase + r;
        const float v = acc[i][j][r] + bias[o];
        Out[base + (size_t)o * 256] = (__bf16)v;
      }
    }
  }
}

// ---------------- fused neighborhood attention + residual ----------------
__device__ __forceinline__ void unpack8(const uint4 v, float* f) {
  const uint32_t u0 = v.x, u1 = v.y, u2 = v.z, u3 = v.w;
  f[0] = __uint_as_float(u0 << 16); f[1] = __uint_as_float(u0 & 0xffff0000u);
  f[2] = __uint_as_float(u1 << 16); f[3] = __uint_as_float(u1 & 0xffff0000u);
  f[4] = __uint_as_float(u2 << 16); f[5] = __uint_as_float(u2 & 0xffff0000u);
  f[6] = __uint_as_float(u3 << 16); f[7] = __uint_as_float(u3 & 0xffff0000u);
}

__global__ __launch_bounds__(256) void attn_kernel(
    const __bf16* __restrict__ Qt, const __bf16* __restrict__ Kt,
    const __bf16* __restrict__ Vt, const float* __restrict__ blue,
    float* __restrict__ out)
{
  const int j   = blockIdx.x;
  const int bid = (j & 7) * 256 + (j >> 3);
  const int cg  = bid & 15;
  const int ti  = (bid >> 4) & 15;
  const int b   = bid >> 8;

  const int tid = threadIdx.x;
  const int tj  = tid & 15;
  const int cl  = tid >> 4;
  const int c   = cg * 16 + cl;

  float q[16];
  {
    const __bf16* p = Qt + ((((size_t)b * 16 + ti) * 256 + c) * 16 + tj) * 16;
    unpack8(*(const uint4*)p, q);
    unpack8(*(const uint4*)(p + 8), q + 8);
  }

  float s[9];
#pragma unroll
  for (int n = 0; n < 9; ++n) {
    const int yi = ti + n / 3 - 1;
    const int yj = tj + n % 3 - 1;
    float dot = 0.0f;
    if (yi >= 0 && yi < 16 && yj >= 0 && yj < 16) {
      const __bf16* p = Kt + ((((size_t)b * 16 + yi) * 256 + c) * 16 + yj) * 16;
      float kf[16];
      unpack8(*(const uint4*)p, kf);
      unpack8(*(const uint4*)(p + 8), kf + 8);
#pragma unroll
      for (int dd = 0; dd < 16; ++dd) dot = fmaf(q[dd], kf[dd], dot);
    }
    s[n] = dot * 0.25f;
  }

  float m = s[0];
#pragma unroll
  for (int n = 1; n < 9; ++n) m = fmaxf(m, s[n]);
  float w[9], denom = 0.0f;
#pragma unroll
  for (int n = 0; n < 9; ++n) { w[n] = __expf(s[n] - m); denom += w[n]; }
  const float inv = 1.0f / denom;

  float o16[16];
#pragma unroll
  for (int dd = 0; dd < 16; ++dd) o16[dd] = 0.0f;
#pragma unroll
  for (int n = 0; n < 9; ++n) {
    const int yi = ti + n / 3 - 1;
    const int yj = tj + n % 3 - 1;
    if (yi >= 0 && yi < 16 && yj >= 0 && yj < 16) {
      const __bf16* p = Vt + ((((size_t)b * 16 + yi) * 256 + c) * 16 + yj) * 16;
      float vf[16];
      unpack8(*(const uint4*)p, vf);
      unpack8(*(const uint4*)(p + 8), vf + 8);
#pragma unroll
      for (int dd = 0; dd < 16; ++dd) o16[dd] = fmaf(w[n], vf[dd], o16[dd]);
    }
  }

  const size_t pbase = ((size_t)b * 256 + c) * 4096 + (size_t)(ti * 4) * 64 + tj * 4;
#pragma unroll
  for (int r = 0; r < 4; ++r) {
    f32x4 bl = *(const f32x4*)(blue + pbase + r * 64);
    f32x4 ov;
#pragma unroll
    for (int j2 = 0; j2 < 4; ++j2) ov[j2] = bl[j2] + o16[r * 4 + j2] * inv;
    *(f32x4*)(out + pbase + r * 64) = ov;
  }
}

// ---------------- launcher ----------------
extern "C" void kernel_launch(void* const* d_in, const int* in_sizes, int n_in,
                              void* d_out, int out_size, void* d_ws, size_t ws_size,
                              hipStream_t stream) {
  const float* blue  = (const float*)d_in[0];
  const float* white = (const float*)d_in[1];
  const float* Wq = (const float*)d_in[2];
  const float* bq = (const float*)d_in[3];
  const float* Wk = (const float*)d_in[4];
  const float* bk = (const float*)d_in[5];
  const float* Wv = (const float*)d_in[6];
  const float* bv = (const float*)d_in[7];
  float* out = (float*)d_out;

  const size_t tsz = (size_t)8 * 256 * 256 * 16;   // QKV elems per tensor
  __bf16* Qt = (__bf16*)d_ws;
  __bf16* Kt = Qt + tsz;
  __bf16* Vt = Kt + tsz;

  const size_t need = (3 * tsz + 3 * 65536) * sizeof(__bf16);
  if (ws_size >= need) {
    __bf16* Wbf = Vt + tsz;
    wprep_kernel<<<96, 256, 0, stream>>>(Wq, Wk, Wv, Wbf);
    gemm_f32lds_kernel<<<1536, 256, 0, stream>>>(blue, white, Wbf, bq, bk, bv, Qt, Kt, Vt);
  } else {
    proj_gemm_kernel<<<1536, 256, 0, stream>>>(blue, white, Wq, bq, Wk, bk, Wv, bv, Qt, Kt, Vt);
  }
  attn_kernel<<<2048, 256, 0, stream>>>(Qt, Kt, Vt, blue, out);
}

// Round 12
// 71.080 us; speedup vs baseline: 1.1628x; 1.0227x over previous
//
#include <hip/hip_runtime.h>
#include <hip/hip_bf16.h>
#include <stdint.h>

typedef float  f32x4  __attribute__((ext_vector_type(4)));
typedef float  f32x2  __attribute__((ext_vector_type(2)));
typedef __bf16 bf16x8 __attribute__((ext_vector_type(8)));

#define LROW 40   // (fallback kernel only)

// ---------------- prep: streaming transpose + weight convert ----------------
// blocks 0..255: one (input, b, ti): X f32 [c][hw] -> Xt bf16 [n][c]
// blocks 256..258: W* f32 -> Wbf bf16 [tensor][o][k] straight copy
__global__ __launch_bounds__(1024) void prep_kernel(
    const float* __restrict__ blue, const float* __restrict__ white,
    const float* __restrict__ Wq, const float* __restrict__ Wk,
    const float* __restrict__ Wv,
    __bf16* __restrict__ Xtb, __bf16* __restrict__ Xtw,
    __bf16* __restrict__ Wbf)
{
  const int bid = blockIdx.x;
  const int tid = threadIdx.x;

  if (bid >= 256) {                       // ---- weights: plain convert
    const int t = bid - 256;
    const float* src = (t == 0) ? Wq : (t == 1) ? Wk : Wv;
    __bf16* dst = Wbf + t * 65536;
#pragma unroll
    for (int it = 0; it < 8; ++it) {
      const int idx = it * 8192 + tid * 8;
      f32x4 v0 = *(const f32x4*)(src + idx);
      f32x4 v1 = *(const f32x4*)(src + idx + 4);
      bf16x8 r;
#pragma unroll
      for (int q = 0; q < 4; ++q) { r[q] = (__bf16)v0[q]; r[q + 4] = (__bf16)v1[q]; }
      *(bf16x8*)(dst + idx) = r;
    }
    return;
  }

  const int srcw = bid >> 7;
  const int rem  = bid & 127;
  const int b    = rem >> 4;
  const int ti   = rem & 15;
  const float* X = srcw ? white : blue;
  __bf16*     Xt = srcw ? Xtw : Xtb;

  const int s  = tid & 7;                 // pair sub-slot
  const int co = (tid >> 3) & 31;         // channel octet
  const int u  = tid >> 8;                // 0..3

  const float* Xb = X + (size_t)b * (256 * 4096);
  __bf16* Xtb2 = Xt + (size_t)b * 4096 * 256;

#pragma unroll
  for (int it = 0; it < 4; ++it) {
    const int p   = u * 32 + it * 8 + s;      // pixel pair 0..127
    const int px  = 2 * p;
    const int r   = px >> 6;                  // hw row within strip (0..3)
    const int col = px & 63;
    const int hw  = (ti * 4 + r) * 64 + col;
    const int d   = r * 4 + (col & 3);        // within-token index (even)
    const int n   = ti * 256 + (col >> 2) * 16 + d;

    bf16x8 e0, e1;
#pragma unroll
    for (int j = 0; j < 8; ++j) {
      const int c = co * 8 + j;
      f32x2 v = *(const f32x2*)(Xb + (size_t)c * 4096 + hw);
      e0[j] = (__bf16)v[0];
      e1[j] = (__bf16)v[1];
    }
    *(bf16x8*)(Xtb2 + (size_t)n * 256 + co * 8)       = e0;
    *(bf16x8*)(Xtb2 + (size_t)(n + 1) * 256 + co * 8) = e1;
  }
}

// ---------------- GEMM: global_load_lds, BK=64, 4 phases ----------------
// 128(o) x 128(px) tile, BK=64, 4 K-steps, double-buffered LDS (64 KB).
// Stage: 8 x GLOAD16/wave (4 A + 4 B), linear LDS dest; source k-chunk
// pre-swizzled slot^=(row&7); ds_read applies the same XOR -> every lane
// gets its canonical chunk (semantics unchanged) and b128 reads are 2-way.
// Counted vmcnt(8) keeps the next stage in flight across barriers.

#define GLOAD16(GS, LD) \
  __builtin_amdgcn_global_load_lds( \
      (const __attribute__((address_space(1))) uint32_t*)(GS), \
      (__attribute__((address_space(3))) uint32_t*)(LD), 16, 0, 0)

__global__ __launch_bounds__(256) void gemm_bk64_kernel(
    const __bf16* __restrict__ Xtb, const __bf16* __restrict__ Xtw,
    const __bf16* __restrict__ Wbf,
    const float* __restrict__ bq, const float* __restrict__ bk,
    const float* __restrict__ bv,
    __bf16* __restrict__ Qt, __bf16* __restrict__ Kt, __bf16* __restrict__ Vt)
{
  __shared__ __bf16 As[2][128 * 64];   // 16 KB each
  __shared__ __bf16 Bs[2][128 * 64];

  // XCD-chunked; same-tile panels {K0,V0,K1,V1,Q0,Q1} adjacent (L2 reuse)
  const int bid = blockIdx.x;                   // 1536 = 8 * 192
  const int lid = (bid & 7) * 192 + (bid >> 3);
  const int nb  = lid / 6;
  const int bt  = lid % 6;
  const int tensor = (bt < 4) ? 1 + (bt & 1) : 0;   // 0:Q 1:K 2:V
  const int ob     = (bt < 4) ? (bt >> 1) : (bt & 1);

  const __bf16* Xt   = (tensor == 0) ? Xtb : Xtw;
  const float*  bias = (tensor == 0) ? bq : (tensor == 1) ? bk : bv;
  __bf16*       Out  = (tensor == 0) ? Qt : (tensor == 1) ? Kt : Vt;
  const __bf16* Wp   = Wbf + tensor * 65536 + ob * 32768;

  const int tid  = threadIdx.x;
  const int lane = tid & 63;
  const int w    = tid >> 6;
  const int wo   = w >> 1;
  const int wn   = w & 1;
  const int lrow = lane & 15;
  const int lks  = lane >> 4;         // k-chunk sub-slot 0..3

  const int o0 = ob * 128;
  const int n0 = nb * 128;

  // ---- staging addressing: instr m covers rows (w*4+m)*8 .. +7, 8 slots
  const __bf16* gAsrc[4];
  const __bf16* gBsrc[4];
  int ldsOff[4];
#pragma unroll
  for (int m = 0; m < 4; ++m) {
    const int i    = w * 4 + m;
    const int row  = i * 8 + (lane >> 3);
    const int slot = lane & 7;
    const int ps   = slot ^ (row & 7);            // source pre-swizzle
    gAsrc[m]  = Wp + (size_t)row * 256 + ps * 8;  // + kk*64
    gBsrc[m]  = Xt + (size_t)(n0 + row) * 256 + ps * 8;
    ldsOff[m] = i * 512;                          // elems (1 KB per instr)
  }

#define STAGE(BUF, KK) do {                                        \
    GLOAD16(gAsrc[0] + (KK) * 64, &As[BUF][ldsOff[0]]);            \
    GLOAD16(gAsrc[1] + (KK) * 64, &As[BUF][ldsOff[1]]);            \
    GLOAD16(gAsrc[2] + (KK) * 64, &As[BUF][ldsOff[2]]);            \
    GLOAD16(gAsrc[3] + (KK) * 64, &As[BUF][ldsOff[3]]);            \
    GLOAD16(gBsrc[0] + (KK) * 64, &Bs[BUF][ldsOff[0]]);            \
    GLOAD16(gBsrc[1] + (KK) * 64, &Bs[BUF][ldsOff[1]]);            \
    GLOAD16(gBsrc[2] + (KK) * 64, &Bs[BUF][ldsOff[2]]);            \
    GLOAD16(gBsrc[3] + (KK) * 64, &Bs[BUF][ldsOff[3]]);            \
  } while (0)

  f32x4 acc[4][4];
#pragma unroll
  for (int i = 0; i < 4; ++i)
#pragma unroll
    for (int j = 0; j < 4; ++j) acc[i][j] = (f32x4)0.0f;

#define COMPUTE(BUF) do {                                                       \
    _Pragma("unroll")                                                           \
    for (int h = 0; h < 2; ++h) {                                               \
      bf16x8 af[4], bfr[4];                                                     \
      _Pragma("unroll")                                                         \
      for (int i = 0; i < 4; ++i) {                                             \
        const int row = wo * 64 + i * 16 + lrow;                                \
        af[i] = *(const bf16x8*)&As[BUF][row * 64 +                             \
                   (((h * 4 + lks) ^ (row & 7)) * 8)];                          \
      }                                                                         \
      _Pragma("unroll")                                                         \
      for (int j = 0; j < 4; ++j) {                                             \
        const int row = wn * 64 + j * 16 + lrow;                                \
        bfr[j] = *(const bf16x8*)&Bs[BUF][row * 64 +                            \
                   (((h * 4 + lks) ^ (row & 7)) * 8)];                          \
      }                                                                         \
      __builtin_amdgcn_s_setprio(1);                                            \
      _Pragma("unroll")                                                         \
      for (int i = 0; i < 4; ++i)                                               \
        _Pragma("unroll")                                                       \
        for (int j = 0; j < 4; ++j)                                             \
          acc[i][j] = __builtin_amdgcn_mfma_f32_16x16x32_bf16(af[i], bfr[j],    \
                                                              acc[i][j], 0,0,0);\
      __builtin_amdgcn_s_setprio(0);                                            \
    }                                                                           \
  } while (0)

#define WAITBAR(N) do {                                                         \
    asm volatile("s_waitcnt vmcnt(" #N ")" ::: "memory");                       \
    __builtin_amdgcn_sched_barrier(0);                                          \
    __builtin_amdgcn_s_barrier();                                               \
    __builtin_amdgcn_sched_barrier(0);                                          \
  } while (0)

#define ENDBAR() do {                                                           \
    asm volatile("s_waitcnt lgkmcnt(0)" ::: "memory");                          \
    __builtin_amdgcn_sched_barrier(0);                                          \
    __builtin_amdgcn_s_barrier();                                               \
    __builtin_amdgcn_sched_barrier(0);                                          \
  } while (0)

  STAGE(0, 0);
  STAGE(1, 1);  WAITBAR(8);  COMPUTE(0);  ENDBAR();
  STAGE(0, 2);  WAITBAR(8);  COMPUTE(1);  ENDBAR();
  STAGE(1, 3);  WAITBAR(8);  COMPUTE(0);  ENDBAR();
                WAITBAR(0);  COMPUTE(1);
#undef WAITBAR
#undef ENDBAR
#undef STAGE
#undef COMPUTE

  // ---- epilogue: bias add, write bf16 layout [b][ti][c][tj][16]
#pragma unroll
  for (int i = 0; i < 4; ++i) {
    const int obase = o0 + wo * 64 + i * 16 + (lane >> 4) * 4;
#pragma unroll
    for (int j = 0; j < 4; ++j) {
      const int n  = n0 + wn * 64 + j * 16 + (lane & 15);
      const int bb = n >> 12;
      const int pp = n & 4095;
      const int tt = pp >> 4;
      const int tii = tt >> 4;
      const int tjj = tt & 15;
      const int dd  = pp & 15;
      const size_t base = ((size_t)(bb * 16 + tii) * 256) * 256 + tjj * 16 + dd;
#pragma unroll
      for (int r = 0; r < 4; ++r) {
        const int o = obase + r;
        const float v = acc[i][j][r] + bias[o];
        Out[base + (size_t)o * 256] = (__bf16)v;
      }
    }
  }
}

// ---------------- fallback: round-2 self-contained projection ----------------
__global__ __launch_bounds__(256) void proj_gemm_kernel(
    const float* __restrict__ blue, const float* __restrict__ white,
    const float* __restrict__ Wq, const float* __restrict__ bq,
    const float* __restrict__ Wk, const float* __restrict__ bk,
    const float* __restrict__ Wv, const float* __restrict__ bv,
    __bf16* __restrict__ Qt, __bf16* __restrict__ Kt, __bf16* __restrict__ Vt)
{
  __shared__ __bf16 As[128 * LROW];
  __shared__ __bf16 Bs[128 * LROW];

  const int bidhw = blockIdx.x;
  const int lid   = (bidhw & 7) * 192 + (bidhw >> 3);
  const int nb    = lid / 6;
  const int bt    = lid % 6;
  const int tensor = (bt < 4) ? 1 + (bt & 1) : 0;
  const int ob     = (bt < 4) ? (bt >> 1) : (bt & 1);

  const float* X    = (tensor == 0) ? blue : white;
  const float* W    = (tensor == 0) ? Wq : (tensor == 1) ? Wk : Wv;
  const float* bias = (tensor == 0) ? bq : (tensor == 1) ? bk : bv;
  __bf16*      Out  = (tensor == 0) ? Qt : (tensor == 1) ? Kt : Vt;

  const int tid  = threadIdx.x;
  const int lane = tid & 63;
  const int wave = tid >> 6;
  const int wo   = wave >> 1;
  const int wn   = wave & 1;

  const int o0 = ob * 128;
  const int n0 = nb * 128;
  const int batch = n0 >> 12;
  const int p0    = n0 & 4095;
  const int tk0   = p0 >> 4;
  const int trow  = tk0 >> 4;
  const int tcol0 = tk0 & 15;
  const float* Xb = X + (size_t)batch * (256 * 4096);

  f32x4 acc[4][4];
#pragma unroll
  for (int i = 0; i < 4; ++i)
#pragma unroll
    for (int j = 0; j < 4; ++j) acc[i][j] = (f32x4)0.0f;

  const int arow  = tid >> 1;
  const int ahalf = tid & 1;
  const int n2   = tid & 63;
  const int ko   = tid >> 6;
  const int nloc = 2 * n2;
  const int tl   = nloc >> 4;
  const int d    = nloc & 15;
  const int hw   = (trow * 4 + (d >> 2)) * 64 + (tcol0 + tl) * 4 + (d & 3);

  const int lrow = lane & 15;
  const int lk   = (lane >> 4) * 8;

  for (int kk = 0; kk < 8; ++kk) {
    const int k0 = kk * 32;
    {
      const float* src = W + (size_t)(o0 + arow) * 256 + k0 + ahalf * 16;
      f32x4 t0 = *(const f32x4*)(src + 0);
      f32x4 t1 = *(const f32x4*)(src + 4);
      f32x4 t2 = *(const f32x4*)(src + 8);
      f32x4 t3 = *(const f32x4*)(src + 12);
      bf16x8 c0, c1;
#pragma unroll
      for (int qq = 0; qq < 4; ++qq) { c0[qq] = (__bf16)t0[qq]; c0[qq + 4] = (__bf16)t1[qq]; }
#pragma unroll
      for (int qq = 0; qq < 4; ++qq) { c1[qq] = (__bf16)t2[qq]; c1[qq + 4] = (__bf16)t3[qq]; }
      __bf16* dst = As + arow * LROW + ahalf * 16;
      *(bf16x8*)(dst + 0) = c0;
      *(bf16x8*)(dst + 8) = c1;
    }
    {
      const float* src = Xb + (size_t)(k0 + ko * 8) * 4096 + hw;
      f32x2 v0 = *(const f32x2*)(src + 0 * 4096);
      f32x2 v1 = *(const f32x2*)(src + 1 * 4096);
      f32x2 v2 = *(const f32x2*)(src + 2 * 4096);
      f32x2 v3 = *(const f32x2*)(src + 3 * 4096);
      f32x2 v4 = *(const f32x2*)(src + 4 * 4096);
      f32x2 v5 = *(const f32x2*)(src + 5 * 4096);
      f32x2 v6 = *(const f32x2*)(src + 6 * 4096);
      f32x2 v7 = *(const f32x2*)(src + 7 * 4096);
      bf16x8 r0, r1;
      r0[0] = (__bf16)v0[0]; r0[1] = (__bf16)v1[0]; r0[2] = (__bf16)v2[0]; r0[3] = (__bf16)v3[0];
      r0[4] = (__bf16)v4[0]; r0[5] = (__bf16)v5[0]; r0[6] = (__bf16)v6[0]; r0[7] = (__bf16)v7[0];
      r1[0] = (__bf16)v0[1]; r1[1] = (__bf16)v1[1]; r1[2] = (__bf16)v2[1]; r1[3] = (__bf16)v3[1];
      r1[4] = (__bf16)v4[1]; r1[5] = (__bf16)v5[1]; r1[6] = (__bf16)v6[1]; r1[7] = (__bf16)v7[1];
      *(bf16x8*)(Bs + (nloc + 0) * LROW + ko * 8) = r0;
      *(bf16x8*)(Bs + (nloc + 1) * LROW + ko * 8) = r1;
    }
    __syncthreads();

    bf16x8 a[4], b[4];
#pragma unroll
    for (int i = 0; i < 4; ++i)
      a[i] = *(const bf16x8*)(As + (wo * 64 + i * 16 + lrow) * LROW + lk);
#pragma unroll
    for (int j = 0; j < 4; ++j)
      b[j] = *(const bf16x8*)(Bs + (wn * 64 + j * 16 + lrow) * LROW + lk);
#pragma unroll
    for (int i = 0; i < 4; ++i)
#pragma unroll
      for (int j = 0; j < 4; ++j)
        acc[i][j] = __builtin_amdgcn_mfma_f32_16x16x32_bf16(a[i], b[j], acc[i][j], 0, 0, 0);
    __syncthreads();
  }

#pragma unroll
  for (int i = 0; i < 4; ++i) {
    const int obase = o0 + wo * 64 + i * 16 + (lane >> 4) * 4;
#pragma unroll
    for (int j = 0; j < 4; ++j) {
      const int n  = n0 + wn * 64 + j * 16 + (lane & 15);
      const int bb = n >> 12;
      const int p  = n & 4095;
      const int tt = p >> 4;
      const int tii = tt >> 4;
      const int tjj = tt & 15;
      const int dd  = p & 15;
      const size_t base = ((size_t)(bb * 16 + tii) * 256) * 256 + tjj * 16 + dd;
#pragma unroll
      for (int r = 0; r < 4; ++r) {
        const int o = obase + r;
        const float v = acc[i][j][r] + bias[o];
        Out[base + (size_t)o * 256] = (__bf16)v;
      }
    }
  }
}

// ---------------- fused neighborhood attention + residual ----------------
__device__ __forceinline__ void unpack8(const uint4 v, float* f) {
  const uint32_t u0 = v.x, u1 = v.y, u2 = v.z, u3 = v.w;
  f[0] = __uint_as_float(u0 << 16); f[1] = __uint_as_float(u0 & 0xffff0000u);
  f[2] = __uint_as_float(u1 << 16); f[3] = __uint_as_float(u1 & 0xffff0000u);
  f[4] = __uint_as_float(u2 << 16); f[5] = __uint_as_float(u2 & 0xffff0000u);
  f[6] = __uint_as_float(u3 << 16); f[7] = __uint_as_float(u3 & 0xffff0000u);
}

__global__ __launch_bounds__(256) void attn_kernel(
    const __bf16* __restrict__ Qt, const __bf16* __restrict__ Kt,
    const __bf16* __restrict__ Vt, const float* __restrict__ blue,
    float* __restrict__ out)
{
  const int j   = blockIdx.x;
  const int bid = (j & 7) * 256 + (j >> 3);
  const int cg  = bid & 15;
  const int ti  = (bid >> 4) & 15;
  const int b   = bid >> 8;

  const int tid = threadIdx.x;
  const int tj  = tid & 15;
  const int cl  = tid >> 4;
  const int c   = cg * 16 + cl;

  float q[16];
  {
    const __bf16* p = Qt + ((((size_t)b * 16 + ti) * 256 + c) * 16 + tj) * 16;
    unpack8(*(const uint4*)p, q);
    unpack8(*(const uint4*)(p + 8), q + 8);
  }

  float s[9];
#pragma unroll
  for (int n = 0; n < 9; ++n) {
    const int yi = ti + n / 3 - 1;
    const int yj = tj + n % 3 - 1;
    float dot = 0.0f;
    if (yi >= 0 && yi < 16 && yj >= 0 && yj < 16) {
      const __bf16* p = Kt + ((((size_t)b * 16 + yi) * 256 + c) * 16 + yj) * 16;
      float kf[16];
      unpack8(*(const uint4*)p, kf);
      unpack8(*(const uint4*)(p + 8), kf + 8);
#pragma unroll
      for (int dd = 0; dd < 16; ++dd) dot = fmaf(q[dd], kf[dd], dot);
    }
    s[n] = dot * 0.25f;
  }

  float m = s[0];
#pragma unroll
  for (int n = 1; n < 9; ++n) m = fmaxf(m, s[n]);
  float w[9], denom = 0.0f;
#pragma unroll
  for (int n = 0; n < 9; ++n) { w[n] = __expf(s[n] - m); denom += w[n]; }
  const float inv = 1.0f / denom;

  float o16[16];
#pragma unroll
  for (int dd = 0; dd < 16; ++dd) o16[dd] = 0.0f;
#pragma unroll
  for (int n = 0; n < 9; ++n) {
    const int yi = ti + n / 3 - 1;
    const int yj = tj + n % 3 - 1;
    if (yi >= 0 && yi < 16 && yj >= 0 && yj < 16) {
      const __bf16* p = Vt + ((((size_t)b * 16 + yi) * 256 + c) * 16 + yj) * 16;
      float vf[16];
      unpack8(*(const uint4*)p, vf);
      unpack8(*(const uint4*)(p + 8), vf + 8);
#pragma unroll
      for (int dd = 0; dd < 16; ++dd) o16[dd] = fmaf(w[n], vf[dd], o16[dd]);
    }
  }

  const size_t pbase = ((size_t)b * 256 + c) * 4096 + (size_t)(ti * 4) * 64 + tj * 4;
#pragma unroll
  for (int r = 0; r < 4; ++r) {
    f32x4 bl = *(const f32x4*)(blue + pbase + r * 64);
    f32x4 ov;
#pragma unroll
    for (int j2 = 0; j2 < 4; ++j2) ov[j2] = bl[j2] + o16[r * 4 + j2] * inv;
    *(f32x4*)(out + pbase + r * 64) = ov;
  }
}

// ---------------- launcher ----------------
extern "C" void kernel_launch(void* const* d_in, const int* in_sizes, int n_in,
                              void* d_out, int out_size, void* d_ws, size_t ws_size,
                              hipStream_t stream) {
  const float* blue  = (const float*)d_in[0];
  const float* white = (const float*)d_in[1];
  const float* Wq = (const float*)d_in[2];
  const float* bq = (const float*)d_in[3];
  const float* Wk = (const float*)d_in[4];
  const float* bk = (const float*)d_in[5];
  const float* Wv = (const float*)d_in[6];
  const float* bv = (const float*)d_in[7];
  float* out = (float*)d_out;

  const size_t tsz = (size_t)8 * 256 * 256 * 16;   // QKV elems per tensor
  const size_t xsz = (size_t)8 * 4096 * 256;       // Xt elems per input
  __bf16* Qt = (__bf16*)d_ws;
  __bf16* Kt = Qt + tsz;
  __bf16* Vt = Kt + tsz;

  const size_t need = (3 * tsz + 2 * xsz + 3 * 65536) * sizeof(__bf16);
  if (ws_size >= need) {
    __bf16* Xtb = Vt + tsz;
    __bf16* Xtw = Xtb + xsz;
    __bf16* Wbf = Xtw + xsz;
    prep_kernel<<<259, 1024, 0, stream>>>(blue, white, Wq, Wk, Wv, Xtb, Xtw, Wbf);
    gemm_bk64_kernel<<<1536, 256, 0, stream>>>(Xtb, Xtw, Wbf, bq, bk, bv, Qt, Kt, Vt);
  } else {
    proj_gemm_kernel<<<1536, 256, 0, stream>>>(blue, white, Wq, bq, Wk, bk, Wv, bv, Qt, Kt, Vt);
  }
  attn_kernel<<<2048, 256, 0, stream>>>(Qt, Kt, Vt, blue, out);
}

// Round 13
// 69.499 us; speedup vs baseline: 1.1892x; 1.0227x over previous
//
#include <hip/hip_runtime.h>
#include <hip/hip_bf16.h>
#include <stdint.h>

typedef float  f32x4  __attribute__((ext_vector_type(4)));
typedef float  f32x2  __attribute__((ext_vector_type(2)));
typedef __bf16 bf16x8 __attribute__((ext_vector_type(8)));

#define LROW 40   // (fallback kernel only)

// ---------------- prep: streaming transpose + weight convert ----------------
// blocks 0..255: one (input, b, ti): X f32 [c][hw] -> Xt bf16 [n][c].
// Thread = (channel-octet co, pixel-quad): 8 x f32x4 strided reads
// (128B segments, 1KB/wave-instr) -> 4 x bf16x8 writes (128B segments).
// blocks 256..258: W* f32 -> Wbf bf16 [tensor][o][k] straight copy
__global__ __launch_bounds__(1024) void prep_kernel(
    const float* __restrict__ blue, const float* __restrict__ white,
    const float* __restrict__ Wq, const float* __restrict__ Wk,
    const float* __restrict__ Wv,
    __bf16* __restrict__ Xtb, __bf16* __restrict__ Xtw,
    __bf16* __restrict__ Wbf)
{
  const int bid = blockIdx.x;
  const int tid = threadIdx.x;

  if (bid >= 256) {                       // ---- weights: plain convert
    const int t = bid - 256;
    const float* src = (t == 0) ? Wq : (t == 1) ? Wk : Wv;
    __bf16* dst = Wbf + t * 65536;
#pragma unroll
    for (int it = 0; it < 8; ++it) {
      const int idx = it * 8192 + tid * 8;
      f32x4 v0 = *(const f32x4*)(src + idx);
      f32x4 v1 = *(const f32x4*)(src + idx + 4);
      bf16x8 r;
#pragma unroll
      for (int q = 0; q < 4; ++q) { r[q] = (__bf16)v0[q]; r[q + 4] = (__bf16)v1[q]; }
      *(bf16x8*)(dst + idx) = r;
    }
    return;
  }

  const int srcw = bid >> 7;
  const int rem  = bid & 127;
  const int b    = rem >> 4;
  const int ti   = rem & 15;
  const float* X = srcw ? white : blue;
  __bf16*     Xt = srcw ? Xtw : Xtb;

  const int s  = tid & 7;                 // quad sub-slot
  const int co = (tid >> 3) & 31;         // channel octet
  const int u  = tid >> 8;                // 0..3

  const float* Xb = X + (size_t)b * (256 * 4096);
  __bf16* Xo = Xt + (size_t)b * 4096 * 256;

#pragma unroll
  for (int it = 0; it < 2; ++it) {
    const int qd = it * 32 + u * 8 + s;       // pixel quad 0..63
    const int r  = qd >> 4;                   // hw row within strip
    const int tj = qd & 15;                   // token column
    const int hw = (ti * 4 + r) * 64 + tj * 4;
    const int n0 = ti * 256 + tj * 16 + r * 4;

    f32x4 v[8];
#pragma unroll
    for (int j = 0; j < 8; ++j)
      v[j] = *(const f32x4*)(Xb + (size_t)(co * 8 + j) * 4096 + hw);

#pragma unroll
    for (int i = 0; i < 4; ++i) {
      bf16x8 e;
#pragma unroll
      for (int j = 0; j < 8; ++j) e[j] = (__bf16)v[j][i];
      *(bf16x8*)(Xo + (size_t)(n0 + i) * 256 + co * 8) = e;
    }
  }
}

// ---------------- GEMM: global_load_lds, BK=64, 4 phases ----------------
// 128(o) x 128(px) tile, BK=64, 4 K-steps, double-buffered LDS (64 KB).
// Stage: 8 x GLOAD16/wave (4 A + 4 B), linear LDS dest; source k-chunk
// pre-swizzled slot^=(row&7); ds_read applies the same XOR -> every lane
// gets its canonical chunk (semantics unchanged) and b128 reads are 2-way.
// Counted vmcnt(8) keeps the next stage in flight across barriers.

#define GLOAD16(GS, LD) \
  __builtin_amdgcn_global_load_lds( \
      (const __attribute__((address_space(1))) uint32_t*)(GS), \
      (__attribute__((address_space(3))) uint32_t*)(LD), 16, 0, 0)

__global__ __launch_bounds__(256) void gemm_bk64_kernel(
    const __bf16* __restrict__ Xtb, const __bf16* __restrict__ Xtw,
    const __bf16* __restrict__ Wbf,
    const float* __restrict__ bq, const float* __restrict__ bk,
    const float* __restrict__ bv,
    __bf16* __restrict__ Qt, __bf16* __restrict__ Kt, __bf16* __restrict__ Vt)
{
  __shared__ __bf16 As[2][128 * 64];   // 16 KB each
  __shared__ __bf16 Bs[2][128 * 64];

  // XCD-chunked; same-tile panels {K0,V0,K1,V1,Q0,Q1} adjacent (L2 reuse)
  const int bid = blockIdx.x;                   // 1536 = 8 * 192
  const int lid = (bid & 7) * 192 + (bid >> 3);
  const int nb  = lid / 6;
  const int bt  = lid % 6;
  const int tensor = (bt < 4) ? 1 + (bt & 1) : 0;   // 0:Q 1:K 2:V
  const int ob     = (bt < 4) ? (bt >> 1) : (bt & 1);

  const __bf16* Xt   = (tensor == 0) ? Xtb : Xtw;
  const float*  bias = (tensor == 0) ? bq : (tensor == 1) ? bk : bv;
  __bf16*       Out  = (tensor == 0) ? Qt : (tensor == 1) ? Kt : Vt;
  const __bf16* Wp   = Wbf + tensor * 65536 + ob * 32768;

  const int tid  = threadIdx.x;
  const int lane = tid & 63;
  const int w    = tid >> 6;
  const int wo   = w >> 1;
  const int wn   = w & 1;
  const int lrow = lane & 15;
  const int lks  = lane >> 4;         // k-chunk sub-slot 0..3

  const int o0 = ob * 128;
  const int n0 = nb * 128;

  // ---- staging addressing: instr m covers rows (w*4+m)*8 .. +7, 8 slots
  const __bf16* gAsrc[4];
  const __bf16* gBsrc[4];
  int ldsOff[4];
#pragma unroll
  for (int m = 0; m < 4; ++m) {
    const int i    = w * 4 + m;
    const int row  = i * 8 + (lane >> 3);
    const int slot = lane & 7;
    const int ps   = slot ^ (row & 7);            // source pre-swizzle
    gAsrc[m]  = Wp + (size_t)row * 256 + ps * 8;  // + kk*64
    gBsrc[m]  = Xt + (size_t)(n0 + row) * 256 + ps * 8;
    ldsOff[m] = i * 512;                          // elems (1 KB per instr)
  }

#define STAGE(BUF, KK) do {                                        \
    GLOAD16(gAsrc[0] + (KK) * 64, &As[BUF][ldsOff[0]]);            \
    GLOAD16(gAsrc[1] + (KK) * 64, &As[BUF][ldsOff[1]]);            \
    GLOAD16(gAsrc[2] + (KK) * 64, &As[BUF][ldsOff[2]]);            \
    GLOAD16(gAsrc[3] + (KK) * 64, &As[BUF][ldsOff[3]]);            \
    GLOAD16(gBsrc[0] + (KK) * 64, &Bs[BUF][ldsOff[0]]);            \
    GLOAD16(gBsrc[1] + (KK) * 64, &Bs[BUF][ldsOff[1]]);            \
    GLOAD16(gBsrc[2] + (KK) * 64, &Bs[BUF][ldsOff[2]]);            \
    GLOAD16(gBsrc[3] + (KK) * 64, &Bs[BUF][ldsOff[3]]);            \
  } while (0)

  f32x4 acc[4][4];
#pragma unroll
  for (int i = 0; i < 4; ++i)
#pragma unroll
    for (int j = 0; j < 4; ++j) acc[i][j] = (f32x4)0.0f;

#define COMPUTE(BUF) do {                                                       \
    _Pragma("unroll")                                                           \
    for (int h = 0; h < 2; ++h) {                                               \
      bf16x8 af[4], bfr[4];                                                     \
      _Pragma("unroll")                                                         \
      for (int i = 0; i < 4; ++i) {                                             \
        const int row = wo * 64 + i * 16 + lrow;                                \
        af[i] = *(const bf16x8*)&As[BUF][row * 64 +                             \
                   (((h * 4 + lks) ^ (row & 7)) * 8)];                          \
      }                                                                         \
      _Pragma("unroll")                                                         \
      for (int j = 0; j < 4; ++j) {                                             \
        const int row = wn * 64 + j * 16 + lrow;                                \
        bfr[j] = *(const bf16x8*)&Bs[BUF][row * 64 +                            \
                   (((h * 4 + lks) ^ (row & 7)) * 8)];                          \
      }                                                                         \
      __builtin_amdgcn_s_setprio(1);                                            \
      _Pragma("unroll")                                                         \
      for (int i = 0; i < 4; ++i)                                               \
        _Pragma("unroll")                                                       \
        for (int j = 0; j < 4; ++j)                                             \
          acc[i][j] = __builtin_amdgcn_mfma_f32_16x16x32_bf16(af[i], bfr[j],    \
                                                              acc[i][j], 0,0,0);\
      __builtin_amdgcn_s_setprio(0);                                            \
    }                                                                           \
  } while (0)

#define WAITBAR(N) do {                                                         \
    asm volatile("s_waitcnt vmcnt(" #N ")" ::: "memory");                       \
    __builtin_amdgcn_sched_barrier(0);                                          \
    __builtin_amdgcn_s_barrier();                                               \
    __builtin_amdgcn_sched_barrier(0);                                          \
  } while (0)

#define ENDBAR() do {                                                           \
    asm volatile("s_waitcnt lgkmcnt(0)" ::: "memory");                          \
    __builtin_amdgcn_sched_barrier(0);                                          \
    __builtin_amdgcn_s_barrier();                                               \
    __builtin_amdgcn_sched_barrier(0);                                          \
  } while (0)

  STAGE(0, 0);
  STAGE(1, 1);  WAITBAR(8);  COMPUTE(0);  ENDBAR();
  STAGE(0, 2);  WAITBAR(8);  COMPUTE(1);  ENDBAR();
  STAGE(1, 3);  WAITBAR(8);  COMPUTE(0);  ENDBAR();
                WAITBAR(0);  COMPUTE(1);
#undef WAITBAR
#undef ENDBAR
#undef STAGE
#undef COMPUTE

  // ---- epilogue: bias add, write bf16 layout [b][ti][c][tj][16]
#pragma unroll
  for (int i = 0; i < 4; ++i) {
    const int obase = o0 + wo * 64 + i * 16 + (lane >> 4) * 4;
#pragma unroll
    for (int j = 0; j < 4; ++j) {
      const int n  = n0 + wn * 64 + j * 16 + (lane & 15);
      const int bb = n >> 12;
      const int pp = n & 4095;
      const int tt = pp >> 4;
      const int tii = tt >> 4;
      const int tjj = tt & 15;
      const int dd  = pp & 15;
      const size_t base = ((size_t)(bb * 16 + tii) * 256) * 256 + tjj * 16 + dd;
#pragma unroll
      for (int r = 0; r < 4; ++r) {
        const int o = obase + r;
        const float v = acc[i][j][r] + bias[o];
        Out[base + (size_t)o * 256] = (__bf16)v;
      }
    }
  }
}

// ---------------- fallback: round-2 self-contained projection ----------------
__global__ __launch_bounds__(256) void proj_gemm_kernel(
    const float* __restrict__ blue, const float* __restrict__ white,
    const float* __restrict__ Wq, const float* __restrict__ bq,
    const float* __restrict__ Wk, const float* __restrict__ bk,
    const float* __restrict__ Wv, const float* __restrict__ bv,
    __bf16* __restrict__ Qt, __bf16* __restrict__ Kt, __bf16* __restrict__ Vt)
{
  __shared__ __bf16 As[128 * LROW];
  __shared__ __bf16 Bs[128 * LROW];

  const int bidhw = blockIdx.x;
  const int lid   = (bidhw & 7) * 192 + (bidhw >> 3);
  const int nb    = lid / 6;
  const int bt    = lid % 6;
  const int tensor = (bt < 4) ? 1 + (bt & 1) : 0;
  const int ob     = (bt < 4) ? (bt >> 1) : (bt & 1);

  const float* X    = (tensor == 0) ? blue : white;
  const float* W    = (tensor == 0) ? Wq : (tensor == 1) ? Wk : Wv;
  const float* bias = (tensor == 0) ? bq : (tensor == 1) ? bk : bv;
  __bf16*      Out  = (tensor == 0) ? Qt : (tensor == 1) ? Kt : Vt;

  const int tid  = threadIdx.x;
  const int lane = tid & 63;
  const int wave = tid >> 6;
  const int wo   = wave >> 1;
  const int wn   = wave & 1;

  const int o0 = ob * 128;
  const int n0 = nb * 128;
  const int batch = n0 >> 12;
  const int p0    = n0 & 4095;
  const int tk0   = p0 >> 4;
  const int trow  = tk0 >> 4;
  const int tcol0 = tk0 & 15;
  const float* Xb = X + (size_t)batch * (256 * 4096);

  f32x4 acc[4][4];
#pragma unroll
  for (int i = 0; i < 4; ++i)
#pragma unroll
    for (int j = 0; j < 4; ++j) acc[i][j] = (f32x4)0.0f;

  const int arow  = tid >> 1;
  const int ahalf = tid & 1;
  const int n2   = tid & 63;
  const int ko   = tid >> 6;
  const int nloc = 2 * n2;
  const int tl   = nloc >> 4;
  const int d    = nloc & 15;
  const int hw   = (trow * 4 + (d >> 2)) * 64 + (tcol0 + tl) * 4 + (d & 3);

  const int lrow = lane & 15;
  const int lk   = (lane >> 4) * 8;

  for (int kk = 0; kk < 8; ++kk) {
    const int k0 = kk * 32;
    {
      const float* src = W + (size_t)(o0 + arow) * 256 + k0 + ahalf * 16;
      f32x4 t0 = *(const f32x4*)(src + 0);
      f32x4 t1 = *(const f32x4*)(src + 4);
      f32x4 t2 = *(const f32x4*)(src + 8);
      f32x4 t3 = *(const f32x4*)(src + 12);
      bf16x8 c0, c1;
#pragma unroll
      for (int qq = 0; qq < 4; ++qq) { c0[qq] = (__bf16)t0[qq]; c0[qq + 4] = (__bf16)t1[qq]; }
#pragma unroll
      for (int qq = 0; qq < 4; ++qq) { c1[qq] = (__bf16)t2[qq]; c1[qq + 4] = (__bf16)t3[qq]; }
      __bf16* dst = As + arow * LROW + ahalf * 16;
      *(bf16x8*)(dst + 0) = c0;
      *(bf16x8*)(dst + 8) = c1;
    }
    {
      const float* src = Xb + (size_t)(k0 + ko * 8) * 4096 + hw;
      f32x2 v0 = *(const f32x2*)(src + 0 * 4096);
      f32x2 v1 = *(const f32x2*)(src + 1 * 4096);
      f32x2 v2 = *(const f32x2*)(src + 2 * 4096);
      f32x2 v3 = *(const f32x2*)(src + 3 * 4096);
      f32x2 v4 = *(const f32x2*)(src + 4 * 4096);
      f32x2 v5 = *(const f32x2*)(src + 5 * 4096);
      f32x2 v6 = *(const f32x2*)(src + 6 * 4096);
      f32x2 v7 = *(const f32x2*)(src + 7 * 4096);
      bf16x8 r0, r1;
      r0[0] = (__bf16)v0[0]; r0[1] = (__bf16)v1[0]; r0[2] = (__bf16)v2[0]; r0[3] = (__bf16)v3[0];
      r0[4] = (__bf16)v4[0]; r0[5] = (__bf16)v5[0]; r0[6] = (__bf16)v6[0]; r0[7] = (__bf16)v7[0];
      r1[0] = (__bf16)v0[1]; r1[1] = (__bf16)v1[1]; r1[2] = (__bf16)v2[1]; r1[3] = (__bf16)v3[1];
      r1[4] = (__bf16)v4[1]; r1[5] = (__bf16)v5[1]; r1[6] = (__bf16)v6[1]; r1[7] = (__bf16)v7[1];
      *(bf16x8*)(Bs + (nloc + 0) * LROW + ko * 8) = r0;
      *(bf16x8*)(Bs + (nloc + 1) * LROW + ko * 8) = r1;
    }
    __syncthreads();

    bf16x8 a[4], b[4];
#pragma unroll
    for (int i = 0; i < 4; ++i)
      a[i] = *(const bf16x8*)(As + (wo * 64 + i * 16 + lrow) * LROW + lk);
#pragma unroll
    for (int j = 0; j < 4; ++j)
      b[j] = *(const bf16x8*)(Bs + (wn * 64 + j * 16 + lrow) * LROW + lk);
#pragma unroll
    for (int i = 0; i < 4; ++i)
#pragma unroll
      for (int j = 0; j < 4; ++j)
        acc[i][j] = __builtin_amdgcn_mfma_f32_16x16x32_bf16(a[i], b[j], acc[i][j], 0, 0, 0);
    __syncthreads();
  }

#pragma unroll
  for (int i = 0; i < 4; ++i) {
    const int obase = o0 + wo * 64 + i * 16 + (lane >> 4) * 4;
#pragma unroll
    for (int j = 0; j < 4; ++j) {
      const int n  = n0 + wn * 64 + j * 16 + (lane & 15);
      const int bb = n >> 12;
      const int p  = n & 4095;
      const int tt = p >> 4;
      const int tii = tt >> 4;
      const int tjj = tt & 15;
      const int dd  = p & 15;
      const size_t base = ((size_t)(bb * 16 + tii) * 256) * 256 + tjj * 16 + dd;
#pragma unroll
      for (int r = 0; r < 4; ++r) {
        const int o = obase + r;
        const float v = acc[i][j][r] + bias[o];
        Out[base + (size_t)o * 256] = (__bf16)v;
      }
    }
  }
}

// ---------------- fused neighborhood attention + residual ----------------
__device__ __forceinline__ void unpack8(const uint4 v, float* f) {
  const uint32_t u0 = v.x, u1 = v.y, u2 = v.z, u3 = v.w;
  f[0] = __uint_as_float(u0 << 16); f[1] = __uint_as_float(u0 & 0xffff0000u);
  f[2] = __uint_as_float(u1 << 16); f[3] = __uint_as_float(u1 & 0xffff0000u);
  f[4] = __uint_as_float(u2 << 16); f[5] = __uint_as_float(u2 & 0xffff0000u);
  f[6] = __uint_as_float(u3 << 16); f[7] = __uint_as_float(u3 & 0xffff0000u);
}

__global__ __launch_bounds__(256) void attn_kernel(
    const __bf16* __restrict__ Qt, const __bf16* __restrict__ Kt,
    const __bf16* __restrict__ Vt, const float* __restrict__ blue,
    float* __restrict__ out)
{
  const int j   = blockIdx.x;
  const int bid = (j & 7) * 256 + (j >> 3);
  const int cg  = bid & 15;
  const int ti  = (bid >> 4) & 15;
  const int b   = bid >> 8;

  const int tid = threadIdx.x;
  const int tj  = tid & 15;
  const int cl  = tid >> 4;
  const int c   = cg * 16 + cl;

  float q[16];
  {
    const __bf16* p = Qt + ((((size_t)b * 16 + ti) * 256 + c) * 16 + tj) * 16;
    unpack8(*(const uint4*)p, q);
    unpack8(*(const uint4*)(p + 8), q + 8);
  }

  float s[9];
#pragma unroll
  for (int n = 0; n < 9; ++n) {
    const int yi = ti + n / 3 - 1;
    const int yj = tj + n % 3 - 1;
    float dot = 0.0f;
    if (yi >= 0 && yi < 16 && yj >= 0 && yj < 16) {
      const __bf16* p = Kt + ((((size_t)b * 16 + yi) * 256 + c) * 16 + yj) * 16;
      float kf[16];
      unpack8(*(const uint4*)p, kf);
      unpack8(*(const uint4*)(p + 8), kf + 8);
#pragma unroll
      for (int dd = 0; dd < 16; ++dd) dot = fmaf(q[dd], kf[dd], dot);
    }
    s[n] = dot * 0.25f;
  }

  float m = s[0];
#pragma unroll
  for (int n = 1; n < 9; ++n) m = fmaxf(m, s[n]);
  float w[9], denom = 0.0f;
#pragma unroll
  for (int n = 0; n < 9; ++n) { w[n] = __expf(s[n] - m); denom += w[n]; }
  const float inv = 1.0f / denom;

  float o16[16];
#pragma unroll
  for (int dd = 0; dd < 16; ++dd) o16[dd] = 0.0f;
#pragma unroll
  for (int n = 0; n < 9; ++n) {
    const int yi = ti + n / 3 - 1;
    const int yj = tj + n % 3 - 1;
    if (yi >= 0 && yi < 16 && yj >= 0 && yj < 16) {
      const __bf16* p = Vt + ((((size_t)b * 16 + yi) * 256 + c) * 16 + yj) * 16;
      float vf[16];
      unpack8(*(const uint4*)p, vf);
      unpack8(*(const uint4*)(p + 8), vf + 8);
#pragma unroll
      for (int dd = 0; dd < 16; ++dd) o16[dd] = fmaf(w[n], vf[dd], o16[dd]);
    }
  }

  const size_t pbase = ((size_t)b * 256 + c) * 4096 + (size_t)(ti * 4) * 64 + tj * 4;
#pragma unroll
  for (int r = 0; r < 4; ++r) {
    f32x4 bl = *(const f32x4*)(blue + pbase + r * 64);
    f32x4 ov;
#pragma unroll
    for (int j2 = 0; j2 < 4; ++j2) ov[j2] = bl[j2] + o16[r * 4 + j2] * inv;
    *(f32x4*)(out + pbase + r * 64) = ov;
  }
}

// ---------------- launcher ----------------
extern "C" void kernel_launch(void* const* d_in, const int* in_sizes, int n_in,
                              void* d_out, int out_size, void* d_ws, size_t ws_size,
                              hipStream_t stream) {
  const float* blue  = (const float*)d_in[0];
  const float* white = (const float*)d_in[1];
  const float* Wq = (const float*)d_in[2];
  const float* bq = (const float*)d_in[3];
  const float* Wk = (const float*)d_in[4];
  const float* bk = (const float*)d_in[5];
  const float* Wv = (const float*)d_in[6];
  const float* bv = (const float*)d_in[7];
  float* out = (float*)d_out;

  const size_t tsz = (size_t)8 * 256 * 256 * 16;   // QKV elems per tensor
  const size_t xsz = (size_t)8 * 4096 * 256;       // Xt elems per input
  __bf16* Qt = (__bf16*)d_ws;
  __bf16* Kt = Qt + tsz;
  __bf16* Vt = Kt + tsz;

  const size_t need = (3 * tsz + 2 * xsz + 3 * 65536) * sizeof(__bf16);
  if (ws_size >= need) {
    __bf16* Xtb = Vt + tsz;
    __bf16* Xtw = Xtb + xsz;
    __bf16* Wbf = Xtw + xsz;
    prep_kernel<<<259, 1024, 0, stream>>>(blue, white, Wq, Wk, Wv, Xtb, Xtw, Wbf);
    gemm_bk64_kernel<<<1536, 256, 0, stream>>>(Xtb, Xtw, Wbf, bq, bk, bv, Qt, Kt, Vt);
  } else {
    proj_gemm_kernel<<<1536, 256, 0, stream>>>(blue, white, Wq, bq, Wk, bk, Wv, bv, Qt, Kt, Vt);
  }
  attn_kernel<<<2048, 256, 0, stream>>>(Qt, Kt, Vt, blue, out);
}